// Round 2
// baseline (275.538 us; speedup 1.0000x reference)
//
#include <hip/hip_runtime.h>
#include <hip/hip_bf16.h>

// Problem constants (B,T,S,D) = (4,2048,4,1024); ALL tensors are float32
// (reference uses jnp.float32 throughout; round-1 garbage error proved the
// buffers are not bf16).
constexpr int Bc = 4;
constexpr int Tc = 2048;
constexpr int Sc = 4;
constexpr int Dc = 1024;
constexpr int BT = Bc * Tc;                 // 8192
constexpr int SD = Sc * Dc;                 // 4096
constexpr int SINKHORN_ITERS = 20;

// ws layout (all float32):
//   float[0..15]  = alpha_res * P[s][r], stored as aH[r*4+s]
//   float[16..19] = alpha_pos * H_pos[r]
//   byte offset 128: float[4096] combined bias (bias_res + bias_pos)
constexpr int WS_CB_BYTE_OFF = 128;

__global__ void prep_kernel(const float* __restrict__ Hres,
                            const float* __restrict__ Hpos,
                            const float* __restrict__ alpha_res,
                            const float* __restrict__ alpha_pos,
                            const float* __restrict__ bias_res,
                            const float* __restrict__ bias_pos,
                            float* __restrict__ ws_f,
                            float* __restrict__ ws_cb) {
    const int tid = threadIdx.x;
    if (tid == 0) {
        // Sinkhorn on the 4x4 matrix, fp32, serial (tiny).
        float P[4][4];
        for (int i = 0; i < 4; ++i) {
            float row[4];
            float m = -3.0e38f;
            for (int j = 0; j < 4; ++j) {
                row[j] = Hres[i * 4 + j];
                m = fmaxf(m, row[j]);
            }
            for (int j = 0; j < 4; ++j) P[i][j] = __expf(row[j] - m);
        }
        for (int it = 0; it < SINKHORN_ITERS; ++it) {
            for (int i = 0; i < 4; ++i) {
                float s = P[i][0] + P[i][1] + P[i][2] + P[i][3] + 1e-8f;
                float r = 1.0f / s;   // hoisted reciprocal
                for (int j = 0; j < 4; ++j) P[i][j] *= r;
            }
            for (int j = 0; j < 4; ++j) {
                float s = P[0][j] + P[1][j] + P[2][j] + P[3][j] + 1e-8f;
                float r = 1.0f / s;
                for (int i = 0; i < 4; ++i) P[i][j] *= r;
            }
        }
        const float ar = alpha_res[0];
        const float ap = alpha_pos[0];
        // einsum 'btsd,sr->btrd': output stream r contracts x stream s with P[s][r].
        for (int r = 0; r < 4; ++r)
            for (int s = 0; s < 4; ++s)
                ws_f[r * 4 + s] = ar * P[s][r];
        for (int r = 0; r < 4; ++r)
            ws_f[16 + r] = ap * Hpos[r];
    }
    // Combined bias (4096 floats), saves one stream of L2 reads in main kernel.
    for (int i = tid; i < SD; i += blockDim.x)
        ws_cb[i] = bias_res[i] + bias_pos[i];
}

__global__ __launch_bounds__(256) void main_kernel(
        const float* __restrict__ x,
        const float* __restrict__ lo,
        const float* __restrict__ ws_f,
        const float* __restrict__ ws_cb,
        float* __restrict__ out) {
    const int idx = blockIdx.x * 256 + threadIdx.x;   // 0 .. BT*D/4-1 (2,097,152)
    const int bt  = idx >> 8;          // D/4 = 256 float4 slots per (b,t)
    const int d0  = (idx & 255) << 2;  // element offset within D

    // Uniform coefficients (L1-broadcast, wave-uniform address).
    const float4 aH0 = reinterpret_cast<const float4*>(ws_f)[0];
    const float4 aH1 = reinterpret_cast<const float4*>(ws_f)[1];
    const float4 aH2 = reinterpret_cast<const float4*>(ws_f)[2];
    const float4 aH3 = reinterpret_cast<const float4*>(ws_f)[3];
    const float4 hp  = reinterpret_cast<const float4*>(ws_f)[4];
    const float aH[4][4] = {{aH0.x, aH0.y, aH0.z, aH0.w},
                            {aH1.x, aH1.y, aH1.z, aH1.w},
                            {aH2.x, aH2.y, aH2.z, aH2.w},
                            {aH3.x, aH3.y, aH3.z, aH3.w}};
    const float hpr[4] = {hp.x, hp.y, hp.z, hp.w};

    const int xbase = bt * SD + d0;    // max 33.5M, fits int32

    float xs[4][4];
#pragma unroll
    for (int s = 0; s < 4; ++s) {
        const float4 v = *reinterpret_cast<const float4*>(x + xbase + s * Dc);
        xs[s][0] = v.x; xs[s][1] = v.y; xs[s][2] = v.z; xs[s][3] = v.w;
    }
    const float4 lv = *reinterpret_cast<const float4*>(lo + bt * Dc + d0);
    const float lf[4] = {lv.x, lv.y, lv.z, lv.w};

#pragma unroll
    for (int r = 0; r < 4; ++r) {
        const float4 cbv = *reinterpret_cast<const float4*>(ws_cb + r * Dc + d0);
        const float cb[4] = {cbv.x, cbv.y, cbv.z, cbv.w};
        float acc[4];
#pragma unroll
        for (int j = 0; j < 4; ++j)
            acc[j] = fmaf(lf[j], hpr[r], xs[r][j] + cb[j]);
#pragma unroll
        for (int s = 0; s < 4; ++s)
#pragma unroll
            for (int j = 0; j < 4; ++j)
                acc[j] = fmaf(xs[s][j], aH[r][s], acc[j]);
        float4 o;
        o.x = acc[0]; o.y = acc[1]; o.z = acc[2]; o.w = acc[3];
        *reinterpret_cast<float4*>(out + xbase + r * Dc) = o;
    }
}

extern "C" void kernel_launch(void* const* d_in, const int* in_sizes, int n_in,
                              void* d_out, int out_size, void* d_ws, size_t ws_size,
                              hipStream_t stream) {
    const float* x         = (const float*)d_in[0];
    const float* layer_out = (const float*)d_in[1];
    const float* H_res     = (const float*)d_in[2];
    const float* H_pos     = (const float*)d_in[3];
    const float* alpha_res = (const float*)d_in[4];
    const float* alpha_pos = (const float*)d_in[5];
    const float* bias_res  = (const float*)d_in[6];
    const float* bias_pos  = (const float*)d_in[7];
    float* out = (float*)d_out;

    float* ws_f  = (float*)d_ws;
    float* ws_cb = (float*)((char*)d_ws + WS_CB_BYTE_OFF);

    prep_kernel<<<1, 256, 0, stream>>>(H_res, H_pos, alpha_res, alpha_pos,
                                       bias_res, bias_pos, ws_f, ws_cb);

    const int nthreads = BT * (Dc / 4);          // 2,097,152
    main_kernel<<<nthreads / 256, 256, 0, stream>>>(x, layer_out, ws_f, ws_cb, out);
}

// Round 4
// 269.573 us; speedup vs baseline: 1.0221x; 1.0221x over previous
//
#include <hip/hip_runtime.h>
#include <hip/hip_bf16.h>

// (B,T,S,D) = (4,2048,4,1024); all tensors float32.
// Single fused kernel: per-block 16-lane sinkhorn (shuffle butterflies, ~1k cyc,
// overlapped across resident blocks) -> LDS broadcast -> streaming main body
// with non-temporal stores (out is single-use; keep x/lo resident in LLC).
constexpr int Bc = 4;
constexpr int Tc = 2048;
constexpr int Sc = 4;
constexpr int Dc = 1024;
constexpr int BT = Bc * Tc;                 // 8192
constexpr int SD = Sc * Dc;                 // 4096
constexpr int SINKHORN_ITERS = 20;

// Native clang vector: __builtin_nontemporal_store rejects HIP_vector_type.
typedef float vfloat4 __attribute__((ext_vector_type(4)));

__global__ __launch_bounds__(256) void fused_kernel(
        const float* __restrict__ x,
        const float* __restrict__ lo,
        const float* __restrict__ Hres,
        const float* __restrict__ Hpos,
        const float* __restrict__ alpha_res,
        const float* __restrict__ alpha_pos,
        const float* __restrict__ bias_res,
        const float* __restrict__ bias_pos,
        float* __restrict__ out) {
    __shared__ float s_aH[16];   // s_aH[r*4+s] = alpha_res * P[s][r]
    __shared__ float s_hp[4];    // alpha_pos * H_pos[r]

    const int tid = threadIdx.x;
    if (tid < 16) {
        // Lane l holds P[i][j], i = l>>2 (row s), j = l&3 (col r).
        const int i = tid >> 2;
        const int j = tid & 3;
        const float h = Hres[i * 4 + j];
        // Row max (over j): butterfly on bits 0,1.
        float m = fmaxf(h, __shfl_xor(h, 1));
        m = fmaxf(m, __shfl_xor(m, 2));
        float P = __expf(h - m);
        for (int it = 0; it < SINKHORN_ITERS; ++it) {
            // Row sum (over j): bits 0,1.
            float s = P + __shfl_xor(P, 1);
            s += __shfl_xor(s, 2);
            P = P / (s + 1e-8f);
            // Col sum (over i): bits 2,3.
            float c = P + __shfl_xor(P, 4);
            c += __shfl_xor(c, 8);
            P = P / (c + 1e-8f);
        }
        // einsum 'btsd,sr->btrd': out stream r contracts x stream s with P[s][r].
        s_aH[j * 4 + i] = alpha_res[0] * P;
        if (i == 0) s_hp[j] = alpha_pos[0] * Hpos[j];
    }
    __syncthreads();

    float aH[4][4];
#pragma unroll
    for (int r = 0; r < 4; ++r)
#pragma unroll
        for (int s = 0; s < 4; ++s) aH[r][s] = s_aH[r * 4 + s];
    const float hpr[4] = {s_hp[0], s_hp[1], s_hp[2], s_hp[3]};

    // One block per (b,t) row: 256 threads x float4 = 1024 elems of D.
    const int bt = blockIdx.x;
    const int d0 = tid << 2;
    const int xbase = bt * SD + d0;   // max 33.5M, fits int32

    float xs[4][4];
#pragma unroll
    for (int s = 0; s < 4; ++s) {
        const vfloat4 v = *reinterpret_cast<const vfloat4*>(x + xbase + s * Dc);
        xs[s][0] = v.x; xs[s][1] = v.y; xs[s][2] = v.z; xs[s][3] = v.w;
    }
    const vfloat4 lv = *reinterpret_cast<const vfloat4*>(lo + bt * Dc + d0);
    const float lf[4] = {lv.x, lv.y, lv.z, lv.w};

#pragma unroll
    for (int r = 0; r < 4; ++r) {
        // Biases are 16 KB each, shared by all 8192 blocks -> L2-resident.
        const vfloat4 br = *reinterpret_cast<const vfloat4*>(bias_res + r * Dc + d0);
        const vfloat4 bp = *reinterpret_cast<const vfloat4*>(bias_pos + r * Dc + d0);
        const float cb[4] = {br.x + bp.x, br.y + bp.y, br.z + bp.z, br.w + bp.w};
        float acc[4];
#pragma unroll
        for (int j = 0; j < 4; ++j)
            acc[j] = fmaf(lf[j], hpr[r], xs[r][j] + cb[j]);
#pragma unroll
        for (int s = 0; s < 4; ++s)
#pragma unroll
            for (int j = 0; j < 4; ++j)
                acc[j] = fmaf(xs[s][j], aH[r][s], acc[j]);
        vfloat4 o;
        o.x = acc[0]; o.y = acc[1]; o.z = acc[2]; o.w = acc[3];
        // Non-temporal: out is write-once, never re-read -> don't evict x/lo
        // from Infinity Cache (working set x+lo = 168 MB < 256 MiB).
        __builtin_nontemporal_store(o, reinterpret_cast<vfloat4*>(out + xbase + r * Dc));
    }
}

extern "C" void kernel_launch(void* const* d_in, const int* in_sizes, int n_in,
                              void* d_out, int out_size, void* d_ws, size_t ws_size,
                              hipStream_t stream) {
    const float* x         = (const float*)d_in[0];
    const float* layer_out = (const float*)d_in[1];
    const float* H_res     = (const float*)d_in[2];
    const float* H_pos     = (const float*)d_in[3];
    const float* alpha_res = (const float*)d_in[4];
    const float* alpha_pos = (const float*)d_in[5];
    const float* bias_res  = (const float*)d_in[6];
    const float* bias_pos  = (const float*)d_in[7];
    float* out = (float*)d_out;

    fused_kernel<<<BT, 256, 0, stream>>>(x, layer_out, H_res, H_pos,
                                         alpha_res, alpha_pos,
                                         bias_res, bias_pos, out);
}

// Round 5
// 267.493 us; speedup vs baseline: 1.0301x; 1.0078x over previous
//
#include <hip/hip_runtime.h>
#include <hip/hip_bf16.h>

// (B,T,S,D) = (4,2048,4,1024); all tensors float32.
// Grid-stride streaming kernel: 2048 blocks x 256 threads, each thread owns a
// fixed d0 column slice and walks 4 bt-tiles. Bias loads hoisted out of the
// loop; known trip count -> compiler unrolls and hoists ~20 independent
// dwordx4 loads per wave (deep MLP; R4's VGPR=32 build had serialized loads
// at 2.3 TB/s). Sinkhorn uses v_rcp_f32 (error ~1e-5 << 0.109 threshold).
constexpr int Bc = 4;
constexpr int Tc = 2048;
constexpr int Sc = 4;
constexpr int Dc = 1024;
constexpr int BT = Bc * Tc;                 // 8192
constexpr int SD = Sc * Dc;                 // 4096
constexpr int SINKHORN_ITERS = 20;
constexpr int NBLK = 2048;                  // 8 blocks/CU; 4 bt-tiles per thread

typedef float vfloat4 __attribute__((ext_vector_type(4)));

__global__ __launch_bounds__(256) void fused_kernel(
        const float* __restrict__ x,
        const float* __restrict__ lo,
        const float* __restrict__ Hres,
        const float* __restrict__ Hpos,
        const float* __restrict__ alpha_res,
        const float* __restrict__ alpha_pos,
        const float* __restrict__ bias_res,
        const float* __restrict__ bias_pos,
        float* __restrict__ out) {
    __shared__ float s_aH[16];   // s_aH[r*4+s] = alpha_res * P[s][r]
    __shared__ float s_hp[4];    // alpha_pos * H_pos[r]

    const int tid = threadIdx.x;
    if (tid < 16) {
        // Lane l holds P[i][j], i = l>>2 (row), j = l&3 (col).
        const int i = tid >> 2;
        const int j = tid & 3;
        const float h = Hres[i * 4 + j];
        float m = fmaxf(h, __shfl_xor(h, 1));
        m = fmaxf(m, __shfl_xor(m, 2));
        float P = __expf(h - m);
        for (int it = 0; it < SINKHORN_ITERS; ++it) {
            float s = P + __shfl_xor(P, 1);
            s += __shfl_xor(s, 2);
            P *= __builtin_amdgcn_rcpf(s + 1e-8f);   // fast rcp: ~1e-5 rel, fine
            float c = P + __shfl_xor(P, 4);
            c += __shfl_xor(c, 8);
            P *= __builtin_amdgcn_rcpf(c + 1e-8f);
        }
        // einsum 'btsd,sr->btrd': out stream r contracts x stream s with P[s][r].
        s_aH[j * 4 + i] = alpha_res[0] * P;
        if (i == 0) s_hp[j] = alpha_pos[0] * Hpos[j];
    }
    __syncthreads();

    float aH[4][4];
#pragma unroll
    for (int r = 0; r < 4; ++r)
#pragma unroll
        for (int s = 0; s < 4; ++s) aH[r][s] = s_aH[r * 4 + s];
    const float hpr[4] = {s_hp[0], s_hp[1], s_hp[2], s_hp[3]};

    // Fixed column slice for this thread; biases hoisted (L2-hit, loaded once).
    const int d0 = tid << 2;
    float cb[4][4];
#pragma unroll
    for (int r = 0; r < 4; ++r) {
        const vfloat4 br = *reinterpret_cast<const vfloat4*>(bias_res + r * Dc + d0);
        const vfloat4 bp = *reinterpret_cast<const vfloat4*>(bias_pos + r * Dc + d0);
        cb[r][0] = br.x + bp.x; cb[r][1] = br.y + bp.y;
        cb[r][2] = br.z + bp.z; cb[r][3] = br.w + bp.w;
    }

    // Grid-stride over bt: 4 tiles per thread, known trip count -> unroll+hoist.
#pragma unroll
    for (int it = 0; it < BT / NBLK; ++it) {
        const int bt = blockIdx.x + it * NBLK;
        const int xbase = bt * SD + d0;   // max 33.5M, fits int32

        float xs[4][4];
#pragma unroll
        for (int s = 0; s < 4; ++s) {
            const vfloat4 v = *reinterpret_cast<const vfloat4*>(x + xbase + s * Dc);
            xs[s][0] = v.x; xs[s][1] = v.y; xs[s][2] = v.z; xs[s][3] = v.w;
        }
        const vfloat4 lv = *reinterpret_cast<const vfloat4*>(lo + bt * Dc + d0);
        const float lf[4] = {lv.x, lv.y, lv.z, lv.w};

#pragma unroll
        for (int r = 0; r < 4; ++r) {
            float acc[4];
#pragma unroll
            for (int j = 0; j < 4; ++j)
                acc[j] = fmaf(lf[j], hpr[r], xs[r][j] + cb[r][j]);
#pragma unroll
            for (int s = 0; s < 4; ++s)
#pragma unroll
                for (int j = 0; j < 4; ++j)
                    acc[j] = fmaf(xs[s][j], aH[r][s], acc[j]);
            vfloat4 o;
            o.x = acc[0]; o.y = acc[1]; o.z = acc[2]; o.w = acc[3];
            __builtin_nontemporal_store(o, reinterpret_cast<vfloat4*>(out + xbase + r * Dc));
        }
    }
}

extern "C" void kernel_launch(void* const* d_in, const int* in_sizes, int n_in,
                              void* d_out, int out_size, void* d_ws, size_t ws_size,
                              hipStream_t stream) {
    const float* x         = (const float*)d_in[0];
    const float* layer_out = (const float*)d_in[1];
    const float* H_res     = (const float*)d_in[2];
    const float* H_pos     = (const float*)d_in[3];
    const float* alpha_res = (const float*)d_in[4];
    const float* alpha_pos = (const float*)d_in[5];
    const float* bias_res  = (const float*)d_in[6];
    const float* bias_pos  = (const float*)d_in[7];
    float* out = (float*)d_out;

    fused_kernel<<<NBLK, 256, 0, stream>>>(x, layer_out, H_res, H_pos,
                                           alpha_res, alpha_pos,
                                           bias_res, bias_pos, out);
}